// Round 1
// baseline (70.332 us; speedup 1.0000x reference)
//
#include <hip/hip_runtime.h>
#include <math.h>

// cost = -(1/N^2) sum_ij sigmoid(p_i p_j) relu(t_i - t_j)
//      = -(1/(2N^2)) sum_ij sigmoid(p_i p_j) |t_i - t_j|
// Separable O(N*PB): sigmoid(p_i p_j) ~= sum_b w_b(p_j) sigmoid(p_i q_b)
//   => S = sum_i sum_b sigmoid(p_i q_b) * M_b(t_i),
//      M_b(t) = sum_j w_b(p_j)|t - t_j|  (exact at TB+1 t-nodes via prefix
//      sums over t-binned (w, w*t) histograms; lerped between nodes).
//
// R1 restructure (vs 69.5us single-launch poll version):
//  - TWO graph nodes instead of tagged-slot publish/poll: kernel boundary
//    provides device-wide visibility, so partials are plain float stores
//    and the reduce kernel is deterministic. Removes all agent-scope
//    acquire/release + s_sleep spin (suspected ~15-20us serial tail).
//  - 256 blocks (NBC=32 x NBL=6 x NIC=8) = 1 block/CU: halves the per-CU
//    redundant Phase-A binning (was 2 blocks/CU each scanning all N).
//  - Guard columns: histogram [TB][NBL+2], real col c at c+1. Both hat
//    atomics under ONE range check (c in [0,NBL]); row stride 8 = shift.

#define TB 64                  // t-bins (TB+1 nodes); one wave64 scans it
#define PB 192                 // p-grid points over [PLO,PHI]
#define NBC 32                 // b-chunks
#define NBL 6                  // b per chunk = PB/NBC
#define NIC 8                  // i-chunks
#define NBLK (NBC * NIC)       // 256 blocks
#define NTHR 256
#define PLO (-5.0f)
#define PHI (5.0f)

__global__ __launch_bounds__(NTHR, 2) void auc_partials(
    const float* __restrict__ t, const float* __restrict__ p,
    float* __restrict__ slots, int N)
{
    __shared__ float sW[TB][NBL + 2];      // guard cols at 0 and NBL+1
    __shared__ float sP[TB][NBL + 2];
    __shared__ float sM[NBL][TB + 1];      // node tables
    __shared__ float s_red[4];

    const int bid = blockIdx.x;
    const int bc  = bid >> 3;              // / NIC
    const int ic  = bid & 7;               // % NIC
    const int B0  = bc * NBL;
    const int tid = threadIdx.x;

    // ---- zero private LDS histograms ----
    for (int idx = tid; idx < TB * (NBL + 2); idx += NTHR) {
        (&sW[0][0])[idx] = 0.0f;
        (&sP[0][0])[idx] = 0.0f;
    }
    __syncthreads();

    // ---- phase A: bin ALL N elements for this block's 6 b-columns ----
    const float pscale = (float)(PB - 1) / (PHI - PLO);
    const int itersA = N / (NTHR * 4);     // 16 for N=16384
    for (int it = 0; it < itersA; ++it) {
        const int j4 = (it * NTHR + tid) * 4;
        const float4 tv = *(const float4*)(t + j4);
        const float4 pv = *(const float4*)(p + j4);
        const float te[4] = {tv.x, tv.y, tv.z, tv.w};
        const float pe[4] = {pv.x, pv.y, pv.z, pv.w};
#pragma unroll
        for (int e = 0; e < 4; ++e) {
            float x = (pe[e] - PLO) * pscale;
            x = fminf(fmaxf(x, 0.0f), (float)(PB - 1) - 1e-4f);
            const int b0 = (int)x;
            const float f = x - (float)b0;
            const int tau = min(max((int)(te[e] * (float)TB), 0), TB - 1);
            const int c = b0 - B0 + 1;     // stored col; real col = c-1
            if ((unsigned)c <= (unsigned)NBL) {   // single guarded window
                const float w0 = 1.0f - f;
                atomicAdd(&sW[tau][c],     w0);
                atomicAdd(&sP[tau][c],     w0 * te[e]);
                atomicAdd(&sW[tau][c + 1], f);
                atomicAdd(&sP[tau][c + 1], f * te[e]);
            }
        }
    }
    __syncthreads();

    // ---- phase B: node tables via one-wave prefix scan ----
    // M_b(g) = g*(2A - Wtot) + (Ptot - 2B), A/B = exclusive prefixes below g
    {
        const int wv = tid >> 6, lane = tid & 63;
        for (int cc = wv; cc < NBL; cc += 4) {   // wave w -> cols w, w+4
            const float w = sW[lane][cc + 1];
            const float q = sP[lane][cc + 1];
            float wi = w, qi = q;          // inclusive scans
#pragma unroll
            for (int off = 1; off < 64; off <<= 1) {
                const float wn = __shfl_up(wi, off, 64);
                const float qn = __shfl_up(qi, off, 64);
                if (lane >= off) { wi += wn; qi += qn; }
            }
            const float Wtot = __shfl(wi, 63, 64);
            const float Ptot = __shfl(qi, 63, 64);
            const float A = wi - w;        // exclusive
            const float B = qi - q;
            const float g = (float)lane * (1.0f / (float)TB);
            sM[cc][lane] = g * (2.0f * A - Wtot) + (Ptot - 2.0f * B);
            if (lane == 63) sM[cc][TB] = Wtot - Ptot;   // node g = 1
        }
    }
    __syncthreads();

    // ---- phase C: partial S over (i-chunk) x (6 owned b's) ----
    const float h = (PHI - PLO) / (float)(PB - 1);
    const float q0 = PLO + (float)B0 * h;
    const int i0 = ic * (N / NIC);
    float acc = 0.0f;
    const int itersC = (N / NIC) / (NTHR * 4);   // 2 for N=16384
    for (int it = 0; it < itersC; ++it) {
        const int i4 = i0 + (it * NTHR + tid) * 4;
        const float4 tv = *(const float4*)(t + i4);
        const float4 pv = *(const float4*)(p + i4);
        const float te[4] = {tv.x, tv.y, tv.z, tv.w};
        const float pe[4] = {pv.x, pv.y, pv.z, pv.w};
#pragma unroll
        for (int e = 0; e < 4; ++e) {
            const float c = pe[e] * -1.44269504088896340736f;  // -log2(e)*p_i
            float x = te[e] * (float)TB;
            const int k = min((int)x, TB - 1);
            const float f = x - (float)k;
#pragma unroll
            for (int cc = 0; cc < NBL; ++cc) {
                const float m0 = sM[cc][k];
                const float m1 = sM[cc][k + 1];
                const float m  = fmaf(f, m1 - m0, m0);          // M_b(t_i)
                const float qb = q0 + (float)cc * h;
                const float ex = __builtin_amdgcn_exp2f(c * qb);
                const float sg = __builtin_amdgcn_rcpf(1.0f + ex);
                acc = fmaf(sg, m, acc);
            }
        }
    }

    // ---- block reduce -> plain partial store (kernel boundary syncs) ----
#pragma unroll
    for (int off = 32; off > 0; off >>= 1)
        acc += __shfl_down(acc, off, 64);
    if ((tid & 63) == 0) s_red[tid >> 6] = acc;
    __syncthreads();
    if (tid == 0)
        slots[bid] = s_red[0] + s_red[1] + s_red[2] + s_red[3];
}

// One block: deterministic fixed-order sum of the 256 partials.
__global__ __launch_bounds__(NTHR) void auc_reduce(
    const float* __restrict__ slots, float* __restrict__ out, float scale)
{
    __shared__ float s_red[4];
    const int tid = threadIdx.x;
    float v = slots[tid];                  // NBLK == NTHR == 256
#pragma unroll
    for (int off = 32; off > 0; off >>= 1)
        v += __shfl_down(v, off, 64);
    if ((tid & 63) == 0) s_red[tid >> 6] = v;
    __syncthreads();
    if (tid == 0)
        out[0] = (s_red[0] + s_red[1] + s_red[2] + s_red[3]) * scale;
}

extern "C" void kernel_launch(void* const* d_in, const int* in_sizes, int n_in,
                              void* d_out, int out_size, void* d_ws, size_t ws_size,
                              hipStream_t stream) {
    const float* y_true = (const float*)d_in[0];
    const float* y_pred = (const float*)d_in[1];
    float* out = (float*)d_out;
    float* slots = (float*)d_ws;
    int N = in_sizes[0];                     // 16384
    float scale = -0.5f / ((float)N * (float)N);

    auc_partials<<<NBLK, NTHR, 0, stream>>>(y_true, y_pred, slots, N);
    auc_reduce<<<1, NTHR, 0, stream>>>(slots, out, scale);
}